// Round 1
// baseline (260.601 us; speedup 1.0000x reference)
//
#include <hip/hip_runtime.h>

#define BATCH 2
#define C 20
#define H 512
#define W 512
#define NPIX (H*W)        // 262144
#define NW 16
#define NH 16
#define K 256
#define NITERS 10
#define SPLIT 4           // each block handles 8 rows x 32 cols = 256 pixels
#define PITCH 260         // LDS tile pitch (floats), 16B-aligned rows, breaks pow2 stride
#define NEG_INF_F (-1.0e10f)
#define PART_STRIDE 189   // 9 neighbors * (20 ch + 1 den)

// ---------------------------------------------------------------- init spf0
// One wave per (b, k, ch): mean of pf over the 32x32 cell (exactly 1024 px).
__global__ void ssn_init_kernel(const float* __restrict__ x,
                                float* __restrict__ spf0) {
    int bi = blockIdx.x;              // B*K*C
    int ch = bi % C;
    int k  = (bi / C) % K;
    int b  = bi / (C * K);
    int ky = k >> 4, kx = k & 15;
    const float* src = x + ((size_t)(b * C + ch)) * NPIX;
    int l = threadIdx.x;
    float s = 0.f;
#pragma unroll
    for (int i = 0; i < 16; ++i) {
        int p = l + 64 * i;
        int y = ky * 32 + (p >> 5);
        int xx = kx * 32 + (p & 31);
        s += src[y * W + xx];
    }
#pragma unroll
    for (int o = 32; o > 0; o >>= 1) s += __shfl_down(s, o);
    if (l == 0) spf0[(b * K + k) * C + ch] = s * (1.0f / 1024.0f);
}

// ---------------------------------------------------------------- iterate
// Block = (b, cell, split): 256 pixels. Phase 0: build spf for 9 neighbor
// cells in LDS (from spf0 at iter 0, else from previous partials). Phase A:
// per-pixel distances + softmax -> w[9]; stash pf,w tiles in LDS. Phase B:
// 189 dot-products -> partial buffer slot (no atomics).
__global__ void ssn_iterate_kernel(const float* __restrict__ x,
                                   const float* __restrict__ spf0,
                                   const float* __restrict__ rpart,
                                   float* __restrict__ wpart,
                                   float* __restrict__ outQ,
                                   float* __restrict__ outX,
                                   int iter, int last) {
    __shared__ float spf_lds[9][C];
    __shared__ float pf_tile[C][PITCH];
    __shared__ float w_tile[9][PITCH];

    int t = threadIdx.x;
    int bi = blockIdx.x;
    int s    = bi & 3;
    int cell = (bi >> 2) & (K - 1);
    int b    = bi >> 10;
    int ky = cell >> 4, kx = cell & 15;

    // ---- phase 0: neighbor spf into LDS
    if (t < 9 * C) {
        int jj = t / C, ch = t % C;
        int ny = ky + jj / 3 - 1, nx = kx + jj % 3 - 1;
        float v = 0.f;
        if (ny >= 0 && ny < NH && nx >= 0 && nx < NW) {
            int cell2 = ny * NW + nx;
            if (iter == 0) {
                v = spf0[(b * K + cell2) * C + ch];
            } else {
                float num = 0.f, den = 0.f;
#pragma unroll
                for (int j2 = 0; j2 < 9; ++j2) {
                    int cy = ny - (j2 / 3 - 1), cx = nx - (j2 % 3 - 1);
                    if (cy >= 0 && cy < NH && cx >= 0 && cx < NW) {
                        const float* p = rpart +
                            (size_t)(b * K + cy * NW + cx) * (SPLIT * PART_STRIDE)
                            + j2 * 21;
#pragma unroll
                        for (int ss = 0; ss < SPLIT; ++ss) {
                            num += p[ss * PART_STRIDE + ch];
                            den += p[ss * PART_STRIDE + 20];
                        }
                    }
                }
                v = num / fmaxf(den, 1e-8f);
            }
        }
        spf_lds[jj][ch] = v;
    }
    __syncthreads();

    // ---- phase A: per-pixel work
    int py = t >> 5, px = t & 31;
    int y  = ky * 32 + s * 8 + py;
    int xx = kx * 32 + px;

    float pf[C];
    const float* xb = x + (size_t)b * C * NPIX + y * W + xx;
#pragma unroll
    for (int ch = 0; ch < C; ++ch) pf[ch] = xb[(size_t)ch * NPIX];

    float nd[9];
#pragma unroll
    for (int j = 0; j < 9; ++j) {
        int ny = ky + j / 3 - 1, nx = kx + j % 3 - 1;
        bool valid = (ny >= 0 && ny < NH && nx >= 0 && nx < NW);
        float d = 0.f;
#pragma unroll
        for (int ch = 0; ch < C; ++ch) {
            float df = pf[ch] - spf_lds[j][ch];
            d += df * df;
        }
        nd[j] = valid ? -d : NEG_INF_F;
    }
    float m = nd[0];
#pragma unroll
    for (int j = 1; j < 9; ++j) m = fmaxf(m, nd[j]);
    float wv[9], wsum = 0.f;
#pragma unroll
    for (int j = 0; j < 9; ++j) { wv[j] = __expf(nd[j] - m); wsum += wv[j]; }
    float inv = 1.0f / wsum;
#pragma unroll
    for (int j = 0; j < 9; ++j) { wv[j] *= inv; w_tile[j][t] = wv[j]; }
#pragma unroll
    for (int ch = 0; ch < C; ++ch) pf_tile[ch][t] = pf[ch];

    if (last) {
        float* q = outQ + (size_t)b * 9 * NPIX + y * W + xx;
#pragma unroll
        for (int j = 0; j < 9; ++j) q[(size_t)j * NPIX] = wv[j];
        float* ox = outX + (size_t)b * C * NPIX + y * W + xx;
#pragma unroll
        for (int ch = 0; ch < C; ++ch) ox[(size_t)ch * NPIX] = pf[ch];
    }
    __syncthreads();

    // ---- phase B: 189 dot-products of length 256 from LDS tiles
    if (t < PART_STRIDE) {
        int j = t / 21, r = t % 21;
        const float4* wt = (const float4*)&w_tile[j][0];
        float acc = 0.f;
        if (r < 20) {
            const float4* pt = (const float4*)&pf_tile[r][0];
#pragma unroll 4
            for (int p = 0; p < 64; ++p) {
                float4 w4 = wt[p];
                float4 f4 = pt[p];
                acc += w4.x * f4.x + w4.y * f4.y + w4.z * f4.z + w4.w * f4.w;
            }
        } else {
#pragma unroll 4
            for (int p = 0; p < 64; ++p) {
                float4 w4 = wt[p];
                acc += w4.x + w4.y + w4.z + w4.w;
            }
        }
        wpart[(size_t)(b * K + cell) * (SPLIT * PART_STRIDE)
              + s * PART_STRIDE + t] = acc;
    }
}

// ---------------------------------------------------------------- finalize
__global__ void ssn_finalize_kernel(const float* __restrict__ part,
                                    float* __restrict__ outSpf) {
    int idx = blockIdx.x * blockDim.x + threadIdx.x;   // B*K*C
    if (idx >= BATCH * K * C) return;
    int ch = idx % C;
    int k  = (idx / C) % K;
    int b  = idx / (C * K);
    int ky = k >> 4, kx = k & 15;
    float num = 0.f, den = 0.f;
#pragma unroll
    for (int j2 = 0; j2 < 9; ++j2) {
        int cy = ky - (j2 / 3 - 1), cx = kx - (j2 % 3 - 1);
        if (cy >= 0 && cy < NH && cx >= 0 && cx < NW) {
            const float* p = part +
                (size_t)(b * K + cy * NW + cx) * (SPLIT * PART_STRIDE) + j2 * 21;
#pragma unroll
            for (int ss = 0; ss < SPLIT; ++ss) {
                num += p[ss * PART_STRIDE + ch];
                den += p[ss * PART_STRIDE + 20];
            }
        }
    }
    outSpf[(b * C + ch) * K + k] = num / fmaxf(den, 1e-8f);
}

// ---------------------------------------------------------------- launch
extern "C" void kernel_launch(void* const* d_in, const int* in_sizes, int n_in,
                              void* d_out, int out_size, void* d_ws, size_t ws_size,
                              hipStream_t stream) {
    const float* x = (const float*)d_in[0];
    float* out = (float*)d_out;
    float* outQ   = out;                                   // B*9*NPIX
    float* outSpf = out + (size_t)BATCH * 9 * NPIX;        // B*C*K
    float* outX   = outSpf + (size_t)BATCH * C * K;        // B*C*NPIX

    float* ws    = (float*)d_ws;
    float* spf0  = ws;                                     // B*K*C
    float* part0 = spf0 + (size_t)BATCH * K * C;           // B*K*SPLIT*189
    float* part1 = part0 + (size_t)BATCH * K * SPLIT * PART_STRIDE;

    ssn_init_kernel<<<BATCH * K * C, 64, 0, stream>>>(x, spf0);

    for (int it = 0; it < NITERS; ++it) {
        const float* rp = (it % 2 == 0) ? part0 : part1;   // unused at it==0
        float*       wp = (it % 2 == 0) ? part1 : part0;
        ssn_iterate_kernel<<<BATCH * K * SPLIT, 256, 0, stream>>>(
            x, spf0, rp, wp, outQ, outX, it, (it == NITERS - 1) ? 1 : 0);
    }
    // it==9 wrote part0
    ssn_finalize_kernel<<<(BATCH * K * C + 255) / 256, 256, 0, stream>>>(part0, outSpf);
}